// Round 3
// baseline (1936.228 us; speedup 1.0000x reference)
//
#include <hip/hip_runtime.h>

// ---------------------------------------------------------------------------
// uOT loss (unbalanced Sinkhorn, eps=0.1, rho=1, 50 iters + extrapolation x2)
// One workgroup (512 threads = 8 waves) per sample; 4 samples.
// Register-resident A-tables; f_update barrier-free.
//   f-update: S[i][j] = sum_m (psi'_m * A[i][m]) * B[j][m]   (MFMA, W in-reg)
//   g-update: P[i][m] = sum_j (a*phi)[i][j] * B[j][m]        (MFMA via V-LDS)
//             t_m = sum_i A[i][m] * P[i][m]                  (reg FMA + shfl)
// ---------------------------------------------------------------------------

typedef __attribute__((ext_vector_type(4))) float f32x4;
typedef __attribute__((ext_vector_type(8))) short short8;

// LDS layout (byte offsets)
#define OFF_V    0         // bf16 [128 i][128 j], swz ^((i&15)<<4)  (g-GEMM A-op)
#define OFF_BF   32768     // bf16 [32 mblk][128 j][8 me]            (f-GEMM B-op)
#define OFF_PSI  98304     // f32[256]
#define OFF_NB   99328     // f32[256]
#define OFF_TB   100352    // f32[256]
#define OFF_TP   101376    // f32[2][256]
#define OFF_RED  103424    // f32[8] (pad 64)
#define OFF_YMX  103488    // f32[256]
#define OFF_YMY  104512    // f32[256]
#define LDS_SIZE 105536

#define TAU_F     0.9090909090909091f     // rho/(rho+eps)
#define TEPS_F    0.09090909090909091f    // tau*eps
#define LAMB_F    0.005354280739427885f   // 0.8*sigmoid(-5)
#define NEG5L2E  -7.213475204444817f      // -(1/(2*eps)) * log2(e)

static __device__ __forceinline__ float pklo(unsigned int u) {
  union { unsigned int i; float f; } v; v.i = u << 16; return v.f;
}
static __device__ __forceinline__ float pkhi(unsigned int u) {
  union { unsigned int i; float f; } v; v.i = u & 0xffff0000u; return v.f;
}
static __device__ __forceinline__ unsigned short f2b(float f) {
  union { float f; unsigned int i; } v; v.f = f;
  unsigned int b = v.i + 0x7fffu + ((v.i >> 16) & 1u);   // RNE
  return (unsigned short)(b >> 16);
}
static __device__ __forceinline__ unsigned int cvtpk(float lo, float hi) {
  unsigned int r;
  asm("v_cvt_pk_bf16_f32 %0, %1, %2" : "=v"(r) : "v"(lo), "v"(hi));
  return r;
}
static __device__ __forceinline__ f32x4 mfma16(uint4 a, uint4 b, f32x4 c) {
  return __builtin_amdgcn_mfma_f32_16x16x32_bf16(
      __builtin_bit_cast(short8, a), __builtin_bit_cast(short8, b), c, 0, 0, 0);
}

// ---- f-update: barrier-free; W-frags built in-register from A_f + psi ----
static __device__ __forceinline__ void f_update(f32x4 fA[2][4],
    const uint4 (&A_f)[2][8], const char* smem, int l, int fj) {
  const float* psi = (const float*)(smem + OFF_PSI);
  #pragma unroll
  for (int it = 0; it < 2; ++it)
    #pragma unroll
    for (int jt = 0; jt < 4; ++jt) { f32x4 z = {0.f, 0.f, 0.f, 0.f}; fA[it][jt] = z; }

  #pragma unroll
  for (int ks = 0; ks < 8; ++ks) {
    int mbase = ks * 32 + 8 * (l >> 4);
    float4 p0 = *(const float4*)(psi + mbase);
    float4 p1 = *(const float4*)(psi + mbase + 4);
    uint4 wf[2];
    #pragma unroll
    for (int it = 0; it < 2; ++it) {
      const unsigned int* ar = (const unsigned int*)&A_f[it][ks];
      unsigned int q0 = cvtpk(pklo(ar[0]) * p0.x, pkhi(ar[0]) * p0.y);
      unsigned int q1 = cvtpk(pklo(ar[1]) * p0.z, pkhi(ar[1]) * p0.w);
      unsigned int q2 = cvtpk(pklo(ar[2]) * p1.x, pkhi(ar[2]) * p1.y);
      unsigned int q3 = cvtpk(pklo(ar[3]) * p1.z, pkhi(ar[3]) * p1.w);
      wf[it] = make_uint4(q0, q1, q2, q3);
    }
    uint4 bfr[4];
    #pragma unroll
    for (int jt = 0; jt < 4; ++jt) {
      int j = fj * 64 + jt * 16 + (l & 15);
      int mblk = ks * 4 + (l >> 4);
      bfr[jt] = *(const uint4*)(smem + OFF_BF + (mblk * 128 + j) * 16);
    }
    #pragma unroll
    for (int it = 0; it < 2; ++it)
      #pragma unroll
      for (int jt = 0; jt < 4; ++jt)
        fA[it][jt] = mfma16(wf[it], bfr[jt], fA[it][jt]);
  }
}

// ---- g-update. mode 0: phase-A (b=1); 1: phase-C (b=new_b); 2: residual ----
static __device__ __forceinline__ void g_update(const f32x4 fA[2][4],
    const uint2 (&A_t)[4][4], const unsigned int (&a_pk)[2][2][4],
    const unsigned short* __restrict__ Bg, char* smem,
    int t, int l, int fi, int fj, int gi, int gm, int mode) {
  // V build: phi = s^{-tau}; V[i][j] = a*phi (bf16, swizzled)
  #pragma unroll
  for (int it = 0; it < 2; ++it)
    #pragma unroll
    for (int jt = 0; jt < 4; ++jt) {
      int j = fj * 64 + jt * 16 + (l & 15);
      #pragma unroll
      for (int e2 = 0; e2 < 2; ++e2) {
        int e = 2 * e2;
        float ph0 = exp2f(-TAU_F * log2f(fA[it][jt][e]));
        float ph1 = exp2f(-TAU_F * log2f(fA[it][jt][e + 1]));
        unsigned int ua0 = a_pk[it][jt >> 1][e];
        unsigned int ua1 = a_pk[it][jt >> 1][e + 1];
        float av0 = (jt & 1) ? pkhi(ua0) : pklo(ua0);
        float av1 = (jt & 1) ? pkhi(ua1) : pklo(ua1);
        unsigned int pk = cvtpk(av0 * ph0, av1 * ph1);
        int i0 = fi * 32 + it * 16 + 4 * (l >> 4) + e;
        *(unsigned short*)(smem + OFF_V + ((i0 * 256 + j * 2) ^ ((i0 & 15) << 4))) =
            (unsigned short)(pk & 0xffffu);
        int i1 = i0 + 1;
        *(unsigned short*)(smem + OFF_V + ((i1 * 256 + j * 2) ^ ((i1 & 15) << 4))) =
            (unsigned short)(pk >> 16);
      }
    }
  __syncthreads();

  f32x4 gA[4][4];
  #pragma unroll
  for (int it = 0; it < 4; ++it)
    #pragma unroll
    for (int mt = 0; mt < 4; ++mt) { f32x4 z = {0.f, 0.f, 0.f, 0.f}; gA[it][mt] = z; }
  #pragma unroll
  for (int ks = 0; ks < 4; ++ks) {          // K = j, 32 per step
    int j0 = ks * 32 + 8 * (l >> 4);
    uint4 vfr[4], bfr[4];
    #pragma unroll
    for (int it = 0; it < 4; ++it) {
      int i = gi * 64 + it * 16 + (l & 15);
      vfr[it] = *(const uint4*)(smem + OFF_V + ((i * 256 + j0 * 2) ^ ((i & 15) << 4)));
    }
    #pragma unroll
    for (int mt = 0; mt < 4; ++mt) {
      int m = gm * 64 + mt * 16 + (l & 15);
      int jblk = ks * 4 + (l >> 4);
      bfr[mt] = *(const uint4*)(Bg + (jblk * 256 + m) * 8);
    }
    #pragma unroll
    for (int it = 0; it < 4; ++it)
      #pragma unroll
      for (int mt = 0; mt < 4; ++mt)
        gA[it][mt] = mfma16(vfr[it], bfr[mt], gA[it][mt]);
  }
  // t-reduce: t_m = sum_i A[i][m] * P[i][m]  (A_t register-resident)
  float* tp = (float*)(smem + OFF_TP);
  #pragma unroll
  for (int mt = 0; mt < 4; ++mt) {
    float acc = 0.f;
    #pragma unroll
    for (int it = 0; it < 4; ++it) {
      uint2 u = A_t[it][mt];
      acc += pklo(u.x) * gA[it][mt][0];
      acc += pkhi(u.x) * gA[it][mt][1];
      acc += pklo(u.y) * gA[it][mt][2];
      acc += pkhi(u.y) * gA[it][mt][3];
    }
    acc += __shfl_xor(acc, 16);
    acc += __shfl_xor(acc, 32);
    if ((l & 48) == 0) tp[gi * 256 + gm * 64 + mt * 16 + (l & 15)] = acc;
  }
  __syncthreads();
  if (t < 256) {
    int m = t;
    float tm = tp[m] + tp[256 + m];
    float* psi = (float*)(smem + OFF_PSI);
    float* nb  = (float*)(smem + OFF_NB);
    float* tb  = (float*)(smem + OFF_TB);
    if (mode == 2) {
      float r   = psi[m] * tm - 1.f;               // residual (b=1 in phase A)
      float nbv = fmaxf(1.f + LAMB_F * r, 1e-8f);  // new_b
      nb[m] = nbv;
      psi[m] = nbv;                                // psi' = new_b * 1 for phase C
    } else {
      float ps = exp2f(-TAU_F * log2f(tm));        // t^{-tau}
      psi[m] = (mode == 1 ? nb[m] : 1.f) * ps;
      tb[m] = tm;
    }
  }
  __syncthreads();
}

__global__ void __launch_bounds__(512, 2)
uot_kernel(const float* __restrict__ dens, const float* __restrict__ pts,
           float* __restrict__ out, unsigned short* __restrict__ ws) {
  extern __shared__ char smem[];
  const int s = blockIdx.x;
  const int t = threadIdx.x;
  const int l = t & 63;
  const int w = t >> 6;
  const int fi = w >> 1, fj = w & 1;   // f-GEMM wave tile: rows 32*fi, cols 64*fj
  const int gi = w >> 2, gm = w & 3;   // g-GEMM wave tile: rows 64*gi, cols 64*gm
  unsigned short* Bg = ws + (size_t)s * 32768;   // B j-blocked [16 jblk][256 m][8 je]
  const float* dp = dens + s * 16384;
  const float* pp = pts + s * 512;
  float* ymx = (float*)(smem + OFF_YMX);
  float* ymy = (float*)(smem + OFF_YMY);
  float* psi = (float*)(smem + OFF_PSI);
  float* nb  = (float*)(smem + OFF_NB);
  unsigned short* BfL = (unsigned short*)(smem + OFF_BF);

  // ---- init ----
  if (t < 256) {
    ymx[t] = pp[2 * t] * (1.f / 256.f);
    ymy[t] = pp[2 * t + 1] * (1.f / 256.f);
    psi[t] = 1.f;
    nb[t]  = 1.f;
  }
  __syncthreads();
  #pragma unroll 1
  for (int r = 0; r < 64; ++r) {
    int flat = r * 512 + t;
    { int me = flat & 7, j = (flat >> 3) & 127, mblk = flat >> 10;
      float dy = (j + 0.5f) * (1.f / 128.f) - ymy[mblk * 8 + me];
      BfL[flat] = f2b(exp2f(dy * dy * NEG5L2E)); }
    { int je = flat & 7, m = (flat >> 3) & 255, jblk = flat >> 11;
      float dy = (jblk * 8 + je + 0.5f) * (1.f / 128.f) - ymy[m];
      Bg[flat] = f2b(exp2f(dy * dy * NEG5L2E)); }
  }
  // ---- register tables ----
  uint4 A_f[2][8];     // f-GEMM A-op layout: i = fi*32+it*16+(l&15), m = ks*32+8*(l>>4)+e
  #pragma unroll
  for (int it = 0; it < 2; ++it) {
    int i = fi * 32 + it * 16 + (l & 15);
    float gx = (i + 0.5f) * (1.f / 128.f);
    #pragma unroll
    for (int ks = 0; ks < 8; ++ks) {
      unsigned int q[4];
      #pragma unroll
      for (int e4 = 0; e4 < 4; ++e4) {
        int m0 = ks * 32 + 8 * (l >> 4) + 2 * e4;
        float d0 = gx - ymx[m0], d1 = gx - ymx[m0 + 1];
        q[e4] = cvtpk(exp2f(d0 * d0 * NEG5L2E), exp2f(d1 * d1 * NEG5L2E));
      }
      A_f[it][ks] = make_uint4(q[0], q[1], q[2], q[3]);
    }
  }
  uint2 A_t[4][4];     // C/D layout: i = gi*64+it*16+4*(l>>4)+e, m = gm*64+mt*16+(l&15)
  #pragma unroll
  for (int it = 0; it < 4; ++it)
    #pragma unroll
    for (int mt = 0; mt < 4; ++mt) {
      int m = gm * 64 + mt * 16 + (l & 15);
      float ym = ymx[m];
      float g0 = (gi * 64 + it * 16 + 4 * (l >> 4) + 0.5f) * (1.f / 128.f);
      float d0 = g0 - ym, d1 = g0 + (1.f / 128.f) - ym;
      float d2 = g0 + (2.f / 128.f) - ym, d3 = g0 + (3.f / 128.f) - ym;
      A_t[it][mt].x = cvtpk(exp2f(d0 * d0 * NEG5L2E), exp2f(d1 * d1 * NEG5L2E));
      A_t[it][mt].y = cvtpk(exp2f(d2 * d2 * NEG5L2E), exp2f(d3 * d3 * NEG5L2E));
    }
  unsigned int a_pk[2][2][4];  // density, C/D layout, packed (jt even lo, jt odd hi)
  #pragma unroll
  for (int it = 0; it < 2; ++it)
    #pragma unroll
    for (int jt2 = 0; jt2 < 2; ++jt2)
      #pragma unroll
      for (int e = 0; e < 4; ++e) {
        int i = fi * 32 + it * 16 + 4 * (l >> 4) + e;
        int j0 = fj * 64 + jt2 * 32 + (l & 15);
        a_pk[it][jt2][e] = cvtpk(fmaxf(dp[i * 128 + j0], 1e-8f),
                                 fmaxf(dp[i * 128 + j0 + 16], 1e-8f));
      }
  __threadfence();
  __syncthreads();

  // ---- two Sinkhorn runs ----
  f32x4 fA[2][4];
  #pragma unroll 1
  for (int phase = 0; phase < 2; ++phase) {
    #pragma unroll 1
    for (int iter = 0; iter < 51; ++iter) {
      f_update(fA, A_f, smem, l, fj);
      if (iter < 50) g_update(fA, A_t, a_pk, Bg, smem, t, l, fi, fj, gi, gm, phase);
    }
    if (phase == 0) g_update(fA, A_t, a_pk, Bg, smem, t, l, fi, fj, gi, gm, 2);
  }

  // ---- loss: 1.05 * ( sum_n a*(1 - s^{tau*eps}) + sum_m nb*(1 - t^{tau*eps}) ) ----
  float ls = 0.f;
  #pragma unroll
  for (int it = 0; it < 2; ++it)
    #pragma unroll
    for (int jt = 0; jt < 4; ++jt)
      #pragma unroll
      for (int e = 0; e < 4; ++e) {
        float sv = fA[it][jt][e];
        unsigned int ua = a_pk[it][jt >> 1][e];
        float av = (jt & 1) ? pkhi(ua) : pklo(ua);
        ls += av * (1.f - exp2f(TEPS_F * log2f(sv)));
      }
  #pragma unroll
  for (int off = 32; off >= 1; off >>= 1) ls += __shfl_xor(ls, off);
  float* red = (float*)(smem + OFF_RED);
  if (l == 0) red[w] = ls;
  float* tp = (float*)(smem + OFF_TP);
  float* tb = (float*)(smem + OFF_TB);
  __syncthreads();
  if (t < 256) tp[t] = nb[t] * (1.f - exp2f(TEPS_F * log2f(tb[t])));
  __syncthreads();
  if (t < 64) {
    float v = tp[t] + tp[t + 64] + tp[t + 128] + tp[t + 192];
    #pragma unroll
    for (int off = 32; off >= 1; off >>= 1) v += __shfl_xor(v, off);
    if (t == 0) {
      float la = 0.f;
      #pragma unroll
      for (int i = 0; i < 8; ++i) la += red[i];
      atomicAdd(out, 1.05f * (la + v));
    }
  }
}

extern "C" void kernel_launch(void* const* d_in, const int* in_sizes, int n_in,
                              void* d_out, int out_size, void* d_ws, size_t ws_size,
                              hipStream_t stream) {
  const float* dens = (const float*)d_in[0];
  const float* pts  = (const float*)d_in[1];
  float* out = (float*)d_out;
  (void)hipMemsetAsync(d_out, 0, (size_t)out_size * sizeof(float), stream);
  if (ws_size < 262144) return;  // 4 samples x 64KB Bg table
  (void)hipFuncSetAttribute(reinterpret_cast<const void*>(uot_kernel),
                            hipFuncAttributeMaxDynamicSharedMemorySize, LDS_SIZE);
  hipLaunchKernelGGL(uot_kernel, dim3(4), dim3(512), LDS_SIZE, stream,
                     dens, pts, out, (unsigned short*)d_ws);
}

// Round 4
// 622.077 us; speedup vs baseline: 3.1125x; 3.1125x over previous
//
#include <hip/hip_runtime.h>

// ---------------------------------------------------------------------------
// uOT loss (unbalanced Sinkhorn, eps=0.1, rho=1, 50 iters + extrapolation x2)
// 8 blocks per sample (32 total, 1 CU each), 512 threads (8 waves) per block.
// Block b of a sample owns tile i in [ib*64,+64), j in [jb*32,+32).
// Per iteration, only each block's partial t^b[256] (1KB) is exchanged via
// global ws + one device-scope barrier; psi recomputed redundantly per block.
//   f-update: S[i][j] = sum_m (psi_m*A[i][m])*B[j][m]   (MFMA, all reg-fed)
//   g-update: P[i][m] = sum_{j local} V[i][j]*B[j][m]   (MFMA, K=32, 1 step)
//             t^b_m = sum_{i local} A[i][m]*P[i][m]     (reg FMA + shfl)
// ---------------------------------------------------------------------------

typedef __attribute__((ext_vector_type(4))) float f32x4;
typedef __attribute__((ext_vector_type(8))) short short8;

#define TAU_F     0.9090909090909091f     // rho/(rho+eps)
#define TEPS_F    0.09090909090909091f    // tau*eps
#define LAMB_F    0.005354280739427885f   // 0.8*sigmoid(-5)
#define NEG5L2E  -7.213475204444817f      // -(1/(2*eps)) * log2(e)

static __device__ __forceinline__ float hexp2(float x) {
  float r; asm("v_exp_f32 %0, %1" : "=v"(r) : "v"(x)); return r;
}
static __device__ __forceinline__ float hlog2(float x) {
  float r; asm("v_log_f32 %0, %1" : "=v"(r) : "v"(x)); return r;
}
static __device__ __forceinline__ float powm(float x, float p) {  // x^p, x>0
  return hexp2(p * hlog2(x));
}
static __device__ __forceinline__ float pklo(unsigned u) {
  union { unsigned i; float f; } v; v.i = u << 16; return v.f;
}
static __device__ __forceinline__ float pkhi(unsigned u) {
  union { unsigned i; float f; } v; v.i = u & 0xffff0000u; return v.f;
}
static __device__ __forceinline__ unsigned cvtpk(float lo, float hi) {
  unsigned r;
  asm("v_cvt_pk_bf16_f32 %0, %1, %2" : "=v"(r) : "v"(lo), "v"(hi));
  return r;
}
static __device__ __forceinline__ f32x4 mfma16(uint4 a, uint4 b, f32x4 c) {
  return __builtin_amdgcn_mfma_f32_16x16x32_bf16(
      __builtin_bit_cast(short8, a), __builtin_bit_cast(short8, b), c, 0, 0, 0);
}

__global__ void __launch_bounds__(512, 2)
uot_kernel(const float* __restrict__ dens, const float* __restrict__ pts,
           float* __restrict__ out, float* __restrict__ ws) {
  __shared__ float ymx[256], ymy[256], psi[256], nb[256], tb[256];
  __shared__ float tp[2][256];
  __shared__ float red[8];
  __shared__ uint4 Vl4[320];                       // V: 64 rows x 80B (40 u16)
  unsigned short* Vl = (unsigned short*)Vl4;

  const int s = blockIdx.x >> 3, b = blockIdx.x & 7;
  const int ib = b >> 2, jb = b & 3;
  const int i0 = ib * 64, j0 = jb * 32;
  const int t = threadIdx.x, l = t & 63, w = t >> 6;
  const int wi = w >> 1, wj = w & 1;   // f-GEMM frag: rows i0+wi*16, cols j0+wj*16
  const int ii = w >> 2, mi = w & 3;   // g-GEMM tile: rows ii*32 (local), cols mi*64
  const int lr = l & 15, lq = l >> 4;

  float* tpart = ws + (size_t)s * 4096;                 // [2 par][8 blk][256]
  unsigned* bar = (unsigned*)(ws + 16384) + 2 * s;      // {cnt, gen}
  const float* dp = dens + s * 16384;
  const float* pp = pts + s * 512;

  if (t < 256) {
    ymx[t] = pp[2 * t] * (1.f / 256.f);
    ymy[t] = pp[2 * t + 1] * (1.f / 256.f);
    psi[t] = 1.f;
    nb[t]  = 1.f;
  }
  __syncthreads();

  // ---- register tables (iteration-invariant) ----
  uint4 A_f[8], B_f[8], B_g[4];
  uint2 A_t[2][4];
  float a_f[4];
  {
    float gxa = (i0 + wi * 16 + lr + 0.5f) * (1.f / 128.f);
    float gya = (j0 + wj * 16 + lr + 0.5f) * (1.f / 128.f);
    #pragma unroll
    for (int ks = 0; ks < 8; ++ks) {
      unsigned qa[4], qb[4];
      #pragma unroll
      for (int e4 = 0; e4 < 4; ++e4) {
        int m0 = ks * 32 + 8 * lq + 2 * e4;
        float dx0 = gxa - ymx[m0], dx1 = gxa - ymx[m0 + 1];
        float dy0 = gya - ymy[m0], dy1 = gya - ymy[m0 + 1];
        qa[e4] = cvtpk(hexp2(dx0 * dx0 * NEG5L2E), hexp2(dx1 * dx1 * NEG5L2E));
        qb[e4] = cvtpk(hexp2(dy0 * dy0 * NEG5L2E), hexp2(dy1 * dy1 * NEG5L2E));
      }
      A_f[ks] = make_uint4(qa[0], qa[1], qa[2], qa[3]);
      B_f[ks] = make_uint4(qb[0], qb[1], qb[2], qb[3]);
    }
    #pragma unroll
    for (int mt = 0; mt < 4; ++mt) {          // B_g: k = local j, col = m
      float ym = ymy[mi * 64 + mt * 16 + lr];
      unsigned q[4];
      #pragma unroll
      for (int e4 = 0; e4 < 4; ++e4) {
        float g0 = (j0 + 8 * lq + 2 * e4 + 0.5f) * (1.f / 128.f);
        float d0 = g0 - ym, d1 = d0 + (1.f / 128.f);
        q[e4] = cvtpk(hexp2(d0 * d0 * NEG5L2E), hexp2(d1 * d1 * NEG5L2E));
      }
      B_g[mt] = make_uint4(q[0], q[1], q[2], q[3]);
    }
    #pragma unroll
    for (int it = 0; it < 2; ++it)            // A_t: C/D layout of g-GEMM
      #pragma unroll
      for (int mt = 0; mt < 4; ++mt) {
        float ym = ymx[mi * 64 + mt * 16 + lr];
        float g0 = (i0 + ii * 32 + it * 16 + 4 * lq + 0.5f) * (1.f / 128.f);
        float d0 = g0 - ym, d1 = d0 + (1.f / 128.f);
        float d2 = d0 + (2.f / 128.f), d3 = d0 + (3.f / 128.f);
        A_t[it][mt].x = cvtpk(hexp2(d0 * d0 * NEG5L2E), hexp2(d1 * d1 * NEG5L2E));
        A_t[it][mt].y = cvtpk(hexp2(d2 * d2 * NEG5L2E), hexp2(d3 * d3 * NEG5L2E));
      }
    #pragma unroll
    for (int e = 0; e < 4; ++e)               // density frag (C/D layout)
      a_f[e] = fmaxf(dp[(i0 + wi * 16 + 4 * lq + e) * 128 + (j0 + wj * 16 + lr)],
                     1e-8f);
  }

  f32x4 fA;
  unsigned mygen = 0;
  int par = 0;

  // ---- f-update: fully register-fed, zero barriers ----
  auto f_update = [&]() {
    f32x4 acc = {0.f, 0.f, 0.f, 0.f};
    #pragma unroll
    for (int ks = 0; ks < 8; ++ks) {
      int mb = ks * 32 + 8 * lq;
      float4 p0 = *(const float4*)(psi + mb);
      float4 p1 = *(const float4*)(psi + mb + 4);
      const unsigned* ar = (const unsigned*)&A_f[ks];
      uint4 wf;
      wf.x = cvtpk(pklo(ar[0]) * p0.x, pkhi(ar[0]) * p0.y);
      wf.y = cvtpk(pklo(ar[1]) * p0.z, pkhi(ar[1]) * p0.w);
      wf.z = cvtpk(pklo(ar[2]) * p1.x, pkhi(ar[2]) * p1.y);
      wf.w = cvtpk(pklo(ar[3]) * p1.z, pkhi(ar[3]) * p1.w);
      acc = mfma16(wf, B_f[ks], acc);
    }
    fA = acc;
  };

  // ---- g-update. mode 0: phase-A; 1: phase-C; 2: residual ----
  auto g_update = [&](int mode) {
    // V build: V[i][j] = a * s^{-tau}  (block-local, bf16)
    #pragma unroll
    for (int e = 0; e < 4; ++e) {
      float phi = powm(fA[e], -TAU_F);
      int il = wi * 16 + 4 * lq + e;
      int jl = wj * 16 + lr;
      union { float f; unsigned i; } v; v.f = a_f[e] * phi;
      unsigned bi = v.i + 0x7fffu + ((v.i >> 16) & 1u);
      Vl[il * 40 + jl] = (unsigned short)(bi >> 16);
    }
    __syncthreads();
    // g-GEMM: K = 32 local j, single MFMA step per frag
    uint4 vfr[2];
    #pragma unroll
    for (int it = 0; it < 2; ++it)
      vfr[it] = *(const uint4*)(Vl + (ii * 32 + it * 16 + lr) * 40 + 8 * lq);
    f32x4 gA[2][4];
    #pragma unroll
    for (int it = 0; it < 2; ++it)
      #pragma unroll
      for (int mt = 0; mt < 4; ++mt) {
        f32x4 z = {0.f, 0.f, 0.f, 0.f};
        gA[it][mt] = mfma16(vfr[it], B_g[mt], z);
      }
    // t-partial: t^b_m = sum_{i local} A[i][m] * P[i][m]
    #pragma unroll
    for (int mt = 0; mt < 4; ++mt) {
      float acc = 0.f;
      #pragma unroll
      for (int it = 0; it < 2; ++it) {
        uint2 u = A_t[it][mt];
        acc += pklo(u.x) * gA[it][mt][0];
        acc += pkhi(u.x) * gA[it][mt][1];
        acc += pklo(u.y) * gA[it][mt][2];
        acc += pkhi(u.y) * gA[it][mt][3];
      }
      acc += __shfl_xor(acc, 16);
      acc += __shfl_xor(acc, 32);
      if (l < 16) tp[ii][mi * 64 + mt * 16 + lr] = acc;
    }
    __syncthreads();
    if (t < 256)
      __hip_atomic_store(&tpart[par * 2048 + b * 256 + t], tp[0][t] + tp[1][t],
                         __ATOMIC_RELAXED, __HIP_MEMORY_SCOPE_AGENT);
    __syncthreads();
    // inter-block barrier (per-sample group of 8)
    if (t == 0) {
      __threadfence();
      unsigned old = __hip_atomic_fetch_add(&bar[0], 1u, __ATOMIC_ACQ_REL,
                                            __HIP_MEMORY_SCOPE_AGENT);
      if (old == 7u) {
        __hip_atomic_store(&bar[0], 0u, __ATOMIC_RELAXED, __HIP_MEMORY_SCOPE_AGENT);
        __hip_atomic_fetch_add(&bar[1], 1u, __ATOMIC_RELEASE,
                               __HIP_MEMORY_SCOPE_AGENT);
      }
      while (__hip_atomic_load(&bar[1], __ATOMIC_ACQUIRE,
                               __HIP_MEMORY_SCOPE_AGENT) == mygen)
        __builtin_amdgcn_s_sleep(1);
      __threadfence();
    }
    mygen++;
    __syncthreads();
    // psi-update (redundant per block, bitwise-consistent)
    if (t < 256) {
      float tm = 0.f;
      #pragma unroll
      for (int k = 0; k < 8; ++k)
        tm += __hip_atomic_load(&tpart[par * 2048 + k * 256 + t],
                                __ATOMIC_RELAXED, __HIP_MEMORY_SCOPE_AGENT);
      if (mode == 2) {
        float r   = psi[t] * tm - 1.f;               // residual (b=1 in phase A)
        float nbv = fmaxf(1.f + LAMB_F * r, 1e-8f);  // new_b
        nb[t] = nbv;
        psi[t] = nbv;                                // psi' for phase C start
      } else {
        float ps = powm(tm, -TAU_F);                 // t^{-tau}
        psi[t] = (mode == 1 ? nb[t] : 1.f) * ps;
        tb[t] = tm;
      }
    }
    par ^= 1;
    __syncthreads();
  };

  // ---- two Sinkhorn runs ----
  #pragma unroll 1
  for (int phase = 0; phase < 2; ++phase) {
    #pragma unroll 1
    for (int iter = 0; iter < 51; ++iter) {
      f_update();
      if (iter < 50) g_update(phase);
    }
    if (phase == 0) g_update(2);
  }

  // ---- loss: 1.05 * ( sum_n a*(1-s^{tau*eps}) + sum_m nb*(1-t^{tau*eps}) ) ----
  float ls = 0.f;
  #pragma unroll
  for (int e = 0; e < 4; ++e)
    ls += a_f[e] * (1.f - powm(fA[e], TEPS_F));
  #pragma unroll
  for (int off = 32; off >= 1; off >>= 1) ls += __shfl_xor(ls, off);
  if (l == 0) red[w] = ls;
  __syncthreads();
  if (t < 256) tp[0][t] = nb[t] * (1.f - powm(tb[t], TEPS_F));
  __syncthreads();
  if (t < 64) {
    float v = (b == 0) ? (tp[0][t] + tp[0][t + 64] + tp[0][t + 128] + tp[0][t + 192])
                       : 0.f;
    #pragma unroll
    for (int off = 32; off >= 1; off >>= 1) v += __shfl_xor(v, off);
    if (t == 0) {
      float la = 0.f;
      #pragma unroll
      for (int k = 0; k < 8; ++k) la += red[k];
      atomicAdd(out, 1.05f * (la + v));
    }
  }
}

extern "C" void kernel_launch(void* const* d_in, const int* in_sizes, int n_in,
                              void* d_out, int out_size, void* d_ws, size_t ws_size,
                              hipStream_t stream) {
  const float* dens = (const float*)d_in[0];
  const float* pts  = (const float*)d_in[1];
  float* out = (float*)d_out;
  if (ws_size < 65600) return;   // 64KB t-partials + barrier words
  (void)hipMemsetAsync(d_out, 0, (size_t)out_size * sizeof(float), stream);
  (void)hipMemsetAsync((char*)d_ws + 65536, 0, 64, stream);   // barrier state
  hipLaunchKernelGGL(uot_kernel, dim3(32), dim3(512), 0, stream,
                     dens, pts, out, (float*)d_ws);
}

// Round 5
// 358.219 us; speedup vs baseline: 5.4052x; 1.7366x over previous
//
#include <hip/hip_runtime.h>

// ---------------------------------------------------------------------------
// uOT loss (unbalanced Sinkhorn, eps=0.1, rho=1, 50 iters + extrapolation x2)
// 8 blocks per sample (32 total, 1 CU each), 512 threads (8 waves) per block.
// Block b of a sample owns tile i in [ib*64,+64), j in [jb*32,+32).
// Per iteration each block publishes its partial t^b[256] (1KB) plus a
// per-block generation flag (own 128B line); peers poll the 8 flags
// (all-to-all flag barrier — no central atomic serialization). Parity
// double-buffer makes the single-flag scheme race-free at depth 2.
//   f-update: S[i][j] = sum_m (psi_m*A[i][m])*B[j][m]   (MFMA, all reg-fed)
//   g-update: P[i][m] = sum_{j local} V[i][j]*B[j][m]   (MFMA, K=32, 1 step)
//             t^b_m = sum_{i local} A[i][m]*P[i][m]     (reg FMA + shfl)
// ---------------------------------------------------------------------------

typedef __attribute__((ext_vector_type(4))) float f32x4;
typedef __attribute__((ext_vector_type(8))) short short8;

#define TAU_F     0.9090909090909091f     // rho/(rho+eps)
#define TEPS_F    0.09090909090909091f    // tau*eps
#define LAMB_F    0.005354280739427885f   // 0.8*sigmoid(-5)
#define NEG5L2E  -7.213475204444817f      // -(1/(2*eps)) * log2(e)

static __device__ __forceinline__ float hexp2(float x) {
  float r; asm("v_exp_f32 %0, %1" : "=v"(r) : "v"(x)); return r;
}
static __device__ __forceinline__ float hlog2(float x) {
  float r; asm("v_log_f32 %0, %1" : "=v"(r) : "v"(x)); return r;
}
static __device__ __forceinline__ float powm(float x, float p) {  // x^p, x>0
  return hexp2(p * hlog2(x));
}
static __device__ __forceinline__ float pklo(unsigned u) {
  union { unsigned i; float f; } v; v.i = u << 16; return v.f;
}
static __device__ __forceinline__ float pkhi(unsigned u) {
  union { unsigned i; float f; } v; v.i = u & 0xffff0000u; return v.f;
}
static __device__ __forceinline__ unsigned cvtpk(float lo, float hi) {
  unsigned r;
  asm("v_cvt_pk_bf16_f32 %0, %1, %2" : "=v"(r) : "v"(lo), "v"(hi));
  return r;
}
static __device__ __forceinline__ f32x4 mfma16(uint4 a, uint4 b, f32x4 c) {
  return __builtin_amdgcn_mfma_f32_16x16x32_bf16(
      __builtin_bit_cast(short8, a), __builtin_bit_cast(short8, b), c, 0, 0, 0);
}

__global__ void __launch_bounds__(512, 2)
uot_kernel(const float* __restrict__ dens, const float* __restrict__ pts,
           float* __restrict__ out, float* __restrict__ ws) {
  __shared__ float ymx[256], ymy[256], psi[256], nb[256], tb[256];
  __shared__ float tp[2][256];
  __shared__ float red[8];
  __shared__ uint4 Vl4[320];                       // V: 64 rows x 80B (40 u16)
  unsigned short* Vl = (unsigned short*)Vl4;

  const int s = blockIdx.x >> 3, b = blockIdx.x & 7;
  const int ib = b >> 2, jb = b & 3;
  const int i0 = ib * 64, j0 = jb * 32;
  const int t = threadIdx.x, l = t & 63, w = t >> 6;
  const int wi = w >> 1, wj = w & 1;   // f-GEMM frag: rows i0+wi*16, cols j0+wj*16
  const int ii = w >> 2, mi = w & 3;   // g-GEMM tile: rows ii*32 (local), cols mi*64
  const int lr = l & 15, lq = l >> 4;

  float* tpart = ws + (size_t)s * 4096;                     // [2 par][8 blk][256]
  unsigned* gens = (unsigned*)((char*)ws + 65536) + s * 256; // 8 flags, 128B apart
  const float* dp = dens + s * 16384;
  const float* pp = pts + s * 512;

  if (t < 256) {
    ymx[t] = pp[2 * t] * (1.f / 256.f);
    ymy[t] = pp[2 * t + 1] * (1.f / 256.f);
    psi[t] = 1.f;
    nb[t]  = 1.f;
  }
  __syncthreads();

  // ---- register tables (iteration-invariant) ----
  uint4 A_f[8], B_f[8], B_g[4];
  uint2 A_t[2][4];
  float a_f[4];
  {
    float gxa = (i0 + wi * 16 + lr + 0.5f) * (1.f / 128.f);
    float gya = (j0 + wj * 16 + lr + 0.5f) * (1.f / 128.f);
    #pragma unroll
    for (int ks = 0; ks < 8; ++ks) {
      unsigned qa[4], qb[4];
      #pragma unroll
      for (int e4 = 0; e4 < 4; ++e4) {
        int m0 = ks * 32 + 8 * lq + 2 * e4;
        float dx0 = gxa - ymx[m0], dx1 = gxa - ymx[m0 + 1];
        float dy0 = gya - ymy[m0], dy1 = gya - ymy[m0 + 1];
        qa[e4] = cvtpk(hexp2(dx0 * dx0 * NEG5L2E), hexp2(dx1 * dx1 * NEG5L2E));
        qb[e4] = cvtpk(hexp2(dy0 * dy0 * NEG5L2E), hexp2(dy1 * dy1 * NEG5L2E));
      }
      A_f[ks] = make_uint4(qa[0], qa[1], qa[2], qa[3]);
      B_f[ks] = make_uint4(qb[0], qb[1], qb[2], qb[3]);
    }
    #pragma unroll
    for (int mt = 0; mt < 4; ++mt) {          // B_g: k = local j, col = m
      float ym = ymy[mi * 64 + mt * 16 + lr];
      unsigned q[4];
      #pragma unroll
      for (int e4 = 0; e4 < 4; ++e4) {
        float g0 = (j0 + 8 * lq + 2 * e4 + 0.5f) * (1.f / 128.f);
        float d0 = g0 - ym, d1 = d0 + (1.f / 128.f);
        q[e4] = cvtpk(hexp2(d0 * d0 * NEG5L2E), hexp2(d1 * d1 * NEG5L2E));
      }
      B_g[mt] = make_uint4(q[0], q[1], q[2], q[3]);
    }
    #pragma unroll
    for (int it = 0; it < 2; ++it)            // A_t: C/D layout of g-GEMM
      #pragma unroll
      for (int mt = 0; mt < 4; ++mt) {
        float ym = ymx[mi * 64 + mt * 16 + lr];
        float g0 = (i0 + ii * 32 + it * 16 + 4 * lq + 0.5f) * (1.f / 128.f);
        float d0 = g0 - ym, d1 = d0 + (1.f / 128.f);
        float d2 = d0 + (2.f / 128.f), d3 = d0 + (3.f / 128.f);
        A_t[it][mt].x = cvtpk(hexp2(d0 * d0 * NEG5L2E), hexp2(d1 * d1 * NEG5L2E));
        A_t[it][mt].y = cvtpk(hexp2(d2 * d2 * NEG5L2E), hexp2(d3 * d3 * NEG5L2E));
      }
    #pragma unroll
    for (int e = 0; e < 4; ++e)               // density frag (C/D layout)
      a_f[e] = fmaxf(dp[(i0 + wi * 16 + 4 * lq + e) * 128 + (j0 + wj * 16 + lr)],
                     1e-8f);
  }

  f32x4 fA;
  unsigned mygen = 0;
  int par = 0;

  // ---- f-update: fully register-fed, zero barriers ----
  auto f_update = [&]() {
    f32x4 acc = {0.f, 0.f, 0.f, 0.f};
    #pragma unroll
    for (int ks = 0; ks < 8; ++ks) {
      int mb = ks * 32 + 8 * lq;
      float4 p0 = *(const float4*)(psi + mb);
      float4 p1 = *(const float4*)(psi + mb + 4);
      const unsigned* ar = (const unsigned*)&A_f[ks];
      uint4 wf;
      wf.x = cvtpk(pklo(ar[0]) * p0.x, pkhi(ar[0]) * p0.y);
      wf.y = cvtpk(pklo(ar[1]) * p0.z, pkhi(ar[1]) * p0.w);
      wf.z = cvtpk(pklo(ar[2]) * p1.x, pkhi(ar[2]) * p1.y);
      wf.w = cvtpk(pklo(ar[3]) * p1.z, pkhi(ar[3]) * p1.w);
      acc = mfma16(wf, B_f[ks], acc);
    }
    fA = acc;
  };

  // ---- g-update. mode 0: phase-A; 1: phase-C; 2: residual ----
  auto g_update = [&](int mode) {
    // V build: V[i][j] = a * s^{-tau}  (block-local, bf16)
    #pragma unroll
    for (int e = 0; e < 4; ++e) {
      float phi = powm(fA[e], -TAU_F);
      int il = wi * 16 + 4 * lq + e;
      int jl = wj * 16 + lr;
      union { float f; unsigned i; } v; v.f = a_f[e] * phi;
      unsigned bi = v.i + 0x7fffu + ((v.i >> 16) & 1u);
      Vl[il * 40 + jl] = (unsigned short)(bi >> 16);
    }
    __syncthreads();
    // g-GEMM: K = 32 local j, single MFMA step per frag
    uint4 vfr[2];
    #pragma unroll
    for (int it = 0; it < 2; ++it)
      vfr[it] = *(const uint4*)(Vl + (ii * 32 + it * 16 + lr) * 40 + 8 * lq);
    f32x4 gA[2][4];
    #pragma unroll
    for (int it = 0; it < 2; ++it)
      #pragma unroll
      for (int mt = 0; mt < 4; ++mt) {
        f32x4 z = {0.f, 0.f, 0.f, 0.f};
        gA[it][mt] = mfma16(vfr[it], B_g[mt], z);
      }
    // t-partial: t^b_m = sum_{i local} A[i][m] * P[i][m]
    #pragma unroll
    for (int mt = 0; mt < 4; ++mt) {
      float acc = 0.f;
      #pragma unroll
      for (int it = 0; it < 2; ++it) {
        uint2 u = A_t[it][mt];
        acc += pklo(u.x) * gA[it][mt][0];
        acc += pkhi(u.x) * gA[it][mt][1];
        acc += pklo(u.y) * gA[it][mt][2];
        acc += pkhi(u.y) * gA[it][mt][3];
      }
      acc += __shfl_xor(acc, 16);
      acc += __shfl_xor(acc, 32);
      if (l < 16) tp[ii][mi * 64 + mt * 16 + lr] = acc;
    }
    __syncthreads();
    // publish partials + own generation flag (all-to-all flag barrier)
    if (t < 256)
      __hip_atomic_store(&tpart[par * 2048 + b * 256 + t], tp[0][t] + tp[1][t],
                         __ATOMIC_RELAXED, __HIP_MEMORY_SCOPE_AGENT);
    __syncthreads();                       // all stores of this block drained
    if (t == 0) {
      __threadfence();
      __hip_atomic_store(&gens[b * 32], mygen + 1, __ATOMIC_RELEASE,
                         __HIP_MEMORY_SCOPE_AGENT);
    }
    if (t < 8) {
      while (__hip_atomic_load(&gens[t * 32], __ATOMIC_ACQUIRE,
                               __HIP_MEMORY_SCOPE_AGENT) < mygen + 1)
        __builtin_amdgcn_s_sleep(1);
    }
    mygen++;
    __syncthreads();
    // psi-update (redundant per block, bitwise-consistent)
    if (t < 256) {
      float tm = 0.f;
      #pragma unroll
      for (int k = 0; k < 8; ++k)
        tm += __hip_atomic_load(&tpart[par * 2048 + k * 256 + t],
                                __ATOMIC_RELAXED, __HIP_MEMORY_SCOPE_AGENT);
      if (mode == 2) {
        float r   = psi[t] * tm - 1.f;               // residual (b=1 in phase A)
        float nbv = fmaxf(1.f + LAMB_F * r, 1e-8f);  // new_b
        nb[t] = nbv;
        psi[t] = nbv;                                // psi' for phase C start
      } else {
        float ps = powm(tm, -TAU_F);                 // t^{-tau}
        psi[t] = (mode == 1 ? nb[t] : 1.f) * ps;
        tb[t] = tm;
      }
    }
    par ^= 1;
    __syncthreads();
  };

  // ---- two Sinkhorn runs ----
  #pragma unroll 1
  for (int phase = 0; phase < 2; ++phase) {
    #pragma unroll 1
    for (int iter = 0; iter < 51; ++iter) {
      f_update();
      if (iter < 50) g_update(phase);
    }
    if (phase == 0) g_update(2);
  }

  // ---- loss: 1.05 * ( sum_n a*(1-s^{tau*eps}) + sum_m nb*(1-t^{tau*eps}) ) ----
  float ls = 0.f;
  #pragma unroll
  for (int e = 0; e < 4; ++e)
    ls += a_f[e] * (1.f - powm(fA[e], TEPS_F));
  #pragma unroll
  for (int off = 32; off >= 1; off >>= 1) ls += __shfl_xor(ls, off);
  if (l == 0) red[w] = ls;
  __syncthreads();
  if (t < 256) tp[0][t] = nb[t] * (1.f - powm(tb[t], TEPS_F));
  __syncthreads();
  if (t < 64) {
    float v = (b == 0) ? (tp[0][t] + tp[0][t + 64] + tp[0][t + 128] + tp[0][t + 192])
                       : 0.f;
    #pragma unroll
    for (int off = 32; off >= 1; off >>= 1) v += __shfl_xor(v, off);
    if (t == 0) {
      float la = 0.f;
      #pragma unroll
      for (int k = 0; k < 8; ++k) la += red[k];
      atomicAdd(out, 1.05f * (la + v));
    }
  }
}

extern "C" void kernel_launch(void* const* d_in, const int* in_sizes, int n_in,
                              void* d_out, int out_size, void* d_ws, size_t ws_size,
                              hipStream_t stream) {
  const float* dens = (const float*)d_in[0];
  const float* pts  = (const float*)d_in[1];
  float* out = (float*)d_out;
  if (ws_size < 69632) return;   // 64KB t-partials + 4KB flags
  (void)hipMemsetAsync(d_out, 0, (size_t)out_size * sizeof(float), stream);
  (void)hipMemsetAsync((char*)d_ws + 65536, 0, 4096, stream);   // gen flags
  hipLaunchKernelGGL(uot_kernel, dim3(32), dim3(512), 0, stream,
                     dens, pts, out, (float*)d_ws);
}

// Round 6
// 271.679 us; speedup vs baseline: 7.1269x; 1.3185x over previous
//
#include <hip/hip_runtime.h>

// ---------------------------------------------------------------------------
// uOT loss (unbalanced Sinkhorn, eps=0.1, rho=1, 50 iters + extrapolation x2)
// 8 blocks per sample (32 total, 1 CU each), 512 threads (8 waves) per block.
// Block b of a sample owns tile i in [ib*64,+64), j in [jb*32,+3 2).
// Exchange: each block publishes t^b[256] as 64-bit (gen<<32|f32) atomic
// words — the generation tag rides with the value, so no fence/flag/extra
// round-trip. Readers poll their own 8 tagged words. Parity double-buffer
// makes the scheme race-free at depth 2.
//   f-update: S[i][j] = sum_m (psi_m*A[i][m])*B[j][m]   (MFMA, all reg-fed)
//   g-update: P[i][m] = sum_{j local} V[i][j]*B[j][m]   (MFMA, K=32, 1 step)
//             t^b_m = sum_{i local} A[i][m]*P[i][m]     (reg FMA + shfl)
// ---------------------------------------------------------------------------

typedef __attribute__((ext_vector_type(4))) float f32x4;
typedef __attribute__((ext_vector_type(8))) short short8;

#define TAU_F     0.9090909090909091f     // rho/(rho+eps)
#define TEPS_F    0.09090909090909091f    // tau*eps == 1-tau (rho=1)
#define LAMB_F    0.005354280739427885f   // 0.8*sigmoid(-5)
#define NEG5L2E  -7.213475204444817f      // -(1/(2*eps)) * log2(e)

static __device__ __forceinline__ float hexp2(float x) {
  float r; asm("v_exp_f32 %0, %1" : "=v"(r) : "v"(x)); return r;
}
static __device__ __forceinline__ float hlog2(float x) {
  float r; asm("v_log_f32 %0, %1" : "=v"(r) : "v"(x)); return r;
}
static __device__ __forceinline__ float powm(float x, float p) {  // x^p, x>0
  return hexp2(p * hlog2(x));
}
static __device__ __forceinline__ float pklo(unsigned u) {
  union { unsigned i; float f; } v; v.i = u << 16; return v.f;
}
static __device__ __forceinline__ float pkhi(unsigned u) {
  union { unsigned i; float f; } v; v.i = u & 0xffff0000u; return v.f;
}
static __device__ __forceinline__ unsigned cvtpk(float lo, float hi) {
  unsigned r;
  asm("v_cvt_pk_bf16_f32 %0, %1, %2" : "=v"(r) : "v"(lo), "v"(hi));
  return r;
}
static __device__ __forceinline__ f32x4 mfma16(uint4 a, uint4 b, f32x4 c) {
  return __builtin_amdgcn_mfma_f32_16x16x32_bf16(
      __builtin_bit_cast(short8, a), __builtin_bit_cast(short8, b), c, 0, 0, 0);
}

__global__ void __launch_bounds__(512, 2)
uot_kernel(const float* __restrict__ dens, const float* __restrict__ pts,
           float* __restrict__ out, unsigned long long* __restrict__ ws) {
  __shared__ float ymx[256], ymy[256], psi[256], nb[256], tb[256];
  __shared__ float tp[2][256];
  __shared__ float red[8];
  __shared__ uint4 Vl4[320];                       // V: 64 rows x 80B (40 u16)
  unsigned short* Vl = (unsigned short*)Vl4;

  const int s = blockIdx.x >> 3, b = blockIdx.x & 7;
  const int ib = b >> 2, jb = b & 3;
  const int i0 = ib * 64, j0 = jb * 32;
  const int t = threadIdx.x, l = t & 63, w = t >> 6;
  const int wi = w >> 1, wj = w & 1;   // f-GEMM frag: rows i0+wi*16, cols j0+wj*16
  const int ii = w >> 2, mi = w & 3;   // g-GEMM tile: rows ii*32 (local), cols mi*64
  const int lr = l & 15, lq = l >> 4;

  unsigned long long* tpair = ws + (size_t)s * 4096;   // [2 par][8 blk][256] u64
  const float* dp = dens + s * 16384;
  const float* pp = pts + s * 512;

  if (t < 256) {
    ymx[t] = pp[2 * t] * (1.f / 256.f);
    ymy[t] = pp[2 * t + 1] * (1.f / 256.f);
    psi[t] = 1.f;
    nb[t]  = 1.f;
  }
  __syncthreads();

  // ---- register tables (iteration-invariant) ----
  uint4 A_f[8], B_f[8], B_g[4];
  uint2 A_t[2][4];
  float a_f[4];
  {
    float gxa = (i0 + wi * 16 + lr + 0.5f) * (1.f / 128.f);
    float gya = (j0 + wj * 16 + lr + 0.5f) * (1.f / 128.f);
    #pragma unroll
    for (int ks = 0; ks < 8; ++ks) {
      unsigned qa[4], qb[4];
      #pragma unroll
      for (int e4 = 0; e4 < 4; ++e4) {
        int m0 = ks * 32 + 8 * lq + 2 * e4;
        float dx0 = gxa - ymx[m0], dx1 = gxa - ymx[m0 + 1];
        float dy0 = gya - ymy[m0], dy1 = gya - ymy[m0 + 1];
        qa[e4] = cvtpk(hexp2(dx0 * dx0 * NEG5L2E), hexp2(dx1 * dx1 * NEG5L2E));
        qb[e4] = cvtpk(hexp2(dy0 * dy0 * NEG5L2E), hexp2(dy1 * dy1 * NEG5L2E));
      }
      A_f[ks] = make_uint4(qa[0], qa[1], qa[2], qa[3]);
      B_f[ks] = make_uint4(qb[0], qb[1], qb[2], qb[3]);
    }
    #pragma unroll
    for (int mt = 0; mt < 4; ++mt) {          // B_g: k = local j, col = m
      float ym = ymy[mi * 64 + mt * 16 + lr];
      unsigned q[4];
      #pragma unroll
      for (int e4 = 0; e4 < 4; ++e4) {
        float g0 = (j0 + 8 * lq + 2 * e4 + 0.5f) * (1.f / 128.f);
        float d0 = g0 - ym, d1 = d0 + (1.f / 128.f);
        q[e4] = cvtpk(hexp2(d0 * d0 * NEG5L2E), hexp2(d1 * d1 * NEG5L2E));
      }
      B_g[mt] = make_uint4(q[0], q[1], q[2], q[3]);
    }
    #pragma unroll
    for (int it = 0; it < 2; ++it)            // A_t: C/D layout of g-GEMM
      #pragma unroll
      for (int mt = 0; mt < 4; ++mt) {
        float ym = ymx[mi * 64 + mt * 16 + lr];
        float g0 = (i0 + ii * 32 + it * 16 + 4 * lq + 0.5f) * (1.f / 128.f);
        float d0 = g0 - ym, d1 = d0 + (1.f / 128.f);
        float d2 = d0 + (2.f / 128.f), d3 = d0 + (3.f / 128.f);
        A_t[it][mt].x = cvtpk(hexp2(d0 * d0 * NEG5L2E), hexp2(d1 * d1 * NEG5L2E));
        A_t[it][mt].y = cvtpk(hexp2(d2 * d2 * NEG5L2E), hexp2(d3 * d3 * NEG5L2E));
      }
    #pragma unroll
    for (int e = 0; e < 4; ++e)               // density frag (C/D layout)
      a_f[e] = fmaxf(dp[(i0 + wi * 16 + 4 * lq + e) * 128 + (j0 + wj * 16 + lr)],
                     1e-8f);
  }

  f32x4 fA;
  unsigned mygen = 0;
  int par = 0;

  // ---- f-update: fully register-fed, zero barriers ----
  auto f_update = [&]() {
    f32x4 acc = {0.f, 0.f, 0.f, 0.f};
    #pragma unroll
    for (int ks = 0; ks < 8; ++ks) {
      int mb = ks * 32 + 8 * lq;
      float4 p0 = *(const float4*)(psi + mb);
      float4 p1 = *(const float4*)(psi + mb + 4);
      const unsigned* ar = (const unsigned*)&A_f[ks];
      uint4 wf;
      wf.x = cvtpk(pklo(ar[0]) * p0.x, pkhi(ar[0]) * p0.y);
      wf.y = cvtpk(pklo(ar[1]) * p0.z, pkhi(ar[1]) * p0.w);
      wf.z = cvtpk(pklo(ar[2]) * p1.x, pkhi(ar[2]) * p1.y);
      wf.w = cvtpk(pklo(ar[3]) * p1.z, pkhi(ar[3]) * p1.w);
      acc = mfma16(wf, B_f[ks], acc);
    }
    fA = acc;
  };

  // ---- g-update. mode 0: phase-A; 1: phase-C; 2: residual ----
  auto g_update = [&](int mode) {
    // V build: V[i][j] = a * s^{-tau}  (block-local, bf16)
    #pragma unroll
    for (int e = 0; e < 4; ++e) {
      float phi = powm(fA[e], -TAU_F);
      int il = wi * 16 + 4 * lq + e;
      int jl = wj * 16 + lr;
      union { float f; unsigned i; } v; v.f = a_f[e] * phi;
      unsigned bi = v.i + 0x7fffu + ((v.i >> 16) & 1u);
      Vl[il * 40 + jl] = (unsigned short)(bi >> 16);
    }
    __syncthreads();
    // g-GEMM: K = 32 local j, single MFMA step per frag
    uint4 vfr[2];
    #pragma unroll
    for (int it = 0; it < 2; ++it)
      vfr[it] = *(const uint4*)(Vl + (ii * 32 + it * 16 + lr) * 40 + 8 * lq);
    f32x4 gA[2][4];
    #pragma unroll
    for (int it = 0; it < 2; ++it)
      #pragma unroll
      for (int mt = 0; mt < 4; ++mt) {
        f32x4 z = {0.f, 0.f, 0.f, 0.f};
        gA[it][mt] = mfma16(vfr[it], B_g[mt], z);
      }
    // t-partial: t^b_m = sum_{i local} A[i][m] * P[i][m]
    #pragma unroll
    for (int mt = 0; mt < 4; ++mt) {
      float acc = 0.f;
      #pragma unroll
      for (int it = 0; it < 2; ++it) {
        uint2 u = A_t[it][mt];
        acc += pklo(u.x) * gA[it][mt][0];
        acc += pkhi(u.x) * gA[it][mt][1];
        acc += pklo(u.y) * gA[it][mt][2];
        acc += pkhi(u.y) * gA[it][mt][3];
      }
      acc += __shfl_xor(acc, 16);
      acc += __shfl_xor(acc, 32);
      if (l < 16) tp[ii][mi * 64 + mt * 16 + lr] = acc;
    }
    __syncthreads();
    const unsigned target = mygen + 1;
    if (t < 256) {
      // publish own (gen|value) word — tag rides with data, no fence needed
      float own = tp[0][t] + tp[1][t];
      union { float f; unsigned i; } ov; ov.f = own;
      unsigned long long pu = ((unsigned long long)target << 32) | ov.i;
      __hip_atomic_store(&tpair[par * 2048 + b * 256 + t], pu,
                         __ATOMIC_RELAXED, __HIP_MEMORY_SCOPE_AGENT);
      // poll all 8 tagged words (incl. own) until generation matches
      float tm;
      bool ok;
      do {
        ok = true; tm = 0.f;
        #pragma unroll
        for (int k = 0; k < 8; ++k) {
          unsigned long long p =
              __hip_atomic_load(&tpair[par * 2048 + k * 256 + t],
                                __ATOMIC_RELAXED, __HIP_MEMORY_SCOPE_AGENT);
          ok &= ((unsigned)(p >> 32) >= target);
          union { unsigned i; float f; } pv; pv.i = (unsigned)p;
          tm += pv.f;
        }
        if (!ok) __builtin_amdgcn_s_sleep(1);
      } while (!ok);
      if (mode == 2) {
        // residual_m = t'^{1-tau} - 1  (uses extrapolated F AND G, as ref)
        float r   = powm(tm, TEPS_F) - 1.f;          // 1-tau == teps for rho=1
        float nbv = fmaxf(1.f + LAMB_F * r, 1e-8f);  // new_b
        nb[t] = nbv;
        psi[t] = nbv;                                // psi' for phase C start
      } else {
        float ps = powm(tm, -TAU_F);                 // t^{-tau}
        psi[t] = (mode == 1 ? nb[t] : 1.f) * ps;
        tb[t] = tm;
      }
    }
    mygen++;
    par ^= 1;
    __syncthreads();
  };

  // ---- two Sinkhorn runs ----
  #pragma unroll 1
  for (int phase = 0; phase < 2; ++phase) {
    #pragma unroll 1
    for (int iter = 0; iter < 51; ++iter) {
      f_update();
      if (iter < 50) g_update(phase);
    }
    if (phase == 0) g_update(2);
  }

  // ---- loss: 1.05 * ( sum_n a*(1-s^{tau*eps}) + sum_m nb*(1-t^{tau*eps}) ) ----
  float ls = 0.f;
  #pragma unroll
  for (int e = 0; e < 4; ++e)
    ls += a_f[e] * (1.f - powm(fA[e], TEPS_F));
  #pragma unroll
  for (int off = 32; off >= 1; off >>= 1) ls += __shfl_xor(ls, off);
  if (l == 0) red[w] = ls;
  __syncthreads();
  if (t < 256) tp[0][t] = nb[t] * (1.f - powm(tb[t], TEPS_F));
  __syncthreads();
  if (t < 64) {
    float v = (b == 0) ? (tp[0][t] + tp[0][t + 64] + tp[0][t + 128] + tp[0][t + 192])
                       : 0.f;
    #pragma unroll
    for (int off = 32; off >= 1; off >>= 1) v += __shfl_xor(v, off);
    if (t == 0) {
      float la = 0.f;
      #pragma unroll
      for (int k = 0; k < 8; ++k) la += red[k];
      atomicAdd(out, 1.05f * (la + v));
    }
  }
}

extern "C" void kernel_launch(void* const* d_in, const int* in_sizes, int n_in,
                              void* d_out, int out_size, void* d_ws, size_t ws_size,
                              hipStream_t stream) {
  const float* dens = (const float*)d_in[0];
  const float* pts  = (const float*)d_in[1];
  float* out = (float*)d_out;
  if (ws_size < 131072) return;   // 4 samples x 32KB (gen|value) pair buffers
  (void)hipMemsetAsync(d_out, 0, (size_t)out_size * sizeof(float), stream);
  (void)hipMemsetAsync(d_ws, 0, 131072, stream);   // gen tags must start at 0
  hipLaunchKernelGGL(uot_kernel, dim3(32), dim3(512), 0, stream,
                     dens, pts, out, (unsigned long long*)d_ws);
}